// Round 1
// baseline (489.829 us; speedup 1.0000x reference)
//
#include <hip/hip_runtime.h>
#include <cstdint>

// ---- problem constants (MoEFeedForward: N=4096, D=1024, F=2048, E=8, top-2) ----
#define N_TOK 4096
#define D_MODEL 1024
#define D_FF 2048
#define D_GU 4096          // 2*D_FF: gate_up row space in w_gate_up
#define N_EXP 8

typedef __bf16 bf16;
typedef __bf16 bf16x8 __attribute__((ext_vector_type(8)));
typedef float f32x4 __attribute__((ext_vector_type(4)));

typedef __attribute__((address_space(1))) void v1_t;
typedef __attribute__((address_space(3))) void v3_t;

// async global->LDS raw copy, 16B/lane; dest = wave-uniform base + lane*16
__device__ __forceinline__ void cp16(void* lds, const void* g) {
  __builtin_amdgcn_global_load_lds((v1_t*)g, (v3_t*)lds, 16, 0, 0);
}

__device__ __forceinline__ f32x4 mfma16(bf16x8 a, bf16x8 b, f32x4 c) {
  return __builtin_amdgcn_mfma_f32_16x16x32_bf16(a, b, c, 0, 0, 0);
}

__device__ __forceinline__ bf16x8 cvt8(float4 a, float4 b) {
  bf16x8 v;
  v[0] = (bf16)a.x; v[1] = (bf16)a.y; v[2] = (bf16)a.z; v[3] = (bf16)a.w;
  v[4] = (bf16)b.x; v[5] = (bf16)b.y; v[6] = (bf16)b.z; v[7] = (bf16)b.w;
  return v;
}

// ======== router: logits->softmax->top2->expert lists; fuses x fp32->bf16 conversion ========
// 32 tokens per block (wave-per-token x 8 iters); LDS-aggregated count atomics.
__global__ __launch_bounds__(256) void router_kernel(
    const float* __restrict__ x, const float* __restrict__ wr,
    int* __restrict__ counts, int* __restrict__ ids, float* __restrict__ wts,
    bf16* __restrict__ xb)
{
  __shared__ int lcnt[N_EXP];
  __shared__ int gbase[N_EXP];
  __shared__ int s_e0[32], s_l0[32], s_e1[32], s_l1[32];
  __shared__ float s_p0[32], s_p1[32];

  const int tid  = threadIdx.x;
  const int wave = tid >> 6;
  const int lane = tid & 63;
  if (tid < N_EXP) lcnt[tid] = 0;
  __syncthreads();

  for (int it = 0; it < 8; ++it) {
    const int li = it * 4 + wave;                 // local token 0..31
    const int token = blockIdx.x * 32 + li;

    const float4* xrow = (const float4*)(x + (size_t)token * D_MODEL + lane * 16);
    float4 x0 = xrow[0], x1 = xrow[1], x2 = xrow[2], x3 = xrow[3];

    // side-product: bf16 copy of x (coalesced 16B stores)
    bf16* xd = xb + (size_t)token * D_MODEL + lane * 16;
    *(bf16x8*)xd       = cvt8(x0, x1);
    *(bf16x8*)(xd + 8) = cvt8(x2, x3);

    float logit[N_EXP];
#pragma unroll
    for (int e = 0; e < N_EXP; ++e) {
      const float4* wrow = (const float4*)(wr + e * D_MODEL + lane * 16);
      float4 w0 = wrow[0], w1 = wrow[1], w2 = wrow[2], w3 = wrow[3];
      float s = x0.x*w0.x + x0.y*w0.y + x0.z*w0.z + x0.w*w0.w
              + x1.x*w1.x + x1.y*w1.y + x1.z*w1.z + x1.w*w1.w
              + x2.x*w2.x + x2.y*w2.y + x2.z*w2.z + x2.w*w2.w
              + x3.x*w3.x + x3.y*w3.y + x3.z*w3.z + x3.w*w3.w;
#pragma unroll
      for (int m = 32; m >= 1; m >>= 1) s += __shfl_xor(s, m);
      logit[e] = fminf(fmaxf(s, -1e4f), 1e4f);    // reference CLAMP
    }

    if (lane == 0) {
      float mx = logit[0];
#pragma unroll
      for (int e = 1; e < N_EXP; ++e) mx = fmaxf(mx, logit[e]);
      float ex[N_EXP], sum = 0.f;
#pragma unroll
      for (int e = 0; e < N_EXP; ++e) { ex[e] = expf(logit[e] - mx); sum += ex[e]; }
      float p[N_EXP];
#pragma unroll
      for (int e = 0; e < N_EXP; ++e)
        p[e] = fminf(fmaxf(ex[e] / (sum + 1e-8f), 1e-8f), 1.0f);
      int e0 = 0;
#pragma unroll
      for (int e = 1; e < N_EXP; ++e) if (p[e] > p[e0]) e0 = e;
      int e1 = (e0 == 0) ? 1 : 0;
#pragma unroll
      for (int e = 0; e < N_EXP; ++e) if (e != e0 && p[e] > p[e1]) e1 = e;
      float p0 = p[e0], p1 = p[e1];
      float inv = 1.f / (p0 + p1 + 1e-8f);
      s_e0[li] = e0; s_l0[li] = atomicAdd(&lcnt[e0], 1); s_p0[li] = p0 * inv;
      s_e1[li] = e1; s_l1[li] = atomicAdd(&lcnt[e1], 1); s_p1[li] = p1 * inv;
    }
  }
  __syncthreads();
  if (tid < N_EXP) gbase[tid] = atomicAdd(&counts[tid], lcnt[tid]);
  __syncthreads();
  if (tid < 32) {
    const int token = blockIdx.x * 32 + tid;
    int e0 = s_e0[tid], e1 = s_e1[tid];
    int a = gbase[e0] + s_l0[tid];
    int b = gbase[e1] + s_l1[tid];
    ids[e0 * N_TOK + a] = token; wts[e0 * N_TOK + a] = s_p0[tid];
    ids[e1 * N_TOK + b] = token; wts[e1 * N_TOK + b] = s_p1[tid];
  }
}

__global__ void offsets_kernel(const int* __restrict__ counts, int* __restrict__ offsets) {
  if (threadIdx.x == 0) {
    int r = 0;
#pragma unroll
    for (int e = 0; e < N_EXP; ++e) { offsets[e] = r; r += counts[e]; }
  }
}

// ============ fp32 -> bf16 bulk convert: 32B load / 16B store per thread ============
__global__ __launch_bounds__(256) void cvt_kernel(
    const float* __restrict__ src, bf16* __restrict__ dst, int n8)
{
  int i = blockIdx.x * 256 + threadIdx.x;
  const int stride = gridDim.x * 256;
  for (; i < n8; i += stride) {
    const float4* s = (const float4*)src + 2 * (size_t)i;
    ((bf16x8*)dst)[i] = cvt8(s[0], s[1]);
  }
}

// ====== GEMM1 (fused gate+up+SwiGLU): gathered xb @ Wgu_b^T for BOTH halves of one
// F-col tile, then H = silu(up)*gate in-epilogue -> H bf16 (compacted rows, pitch 2048).
// m97 skeleton: 128-row tile, BK=32, but 32 MFMA/wave between barriers (2x amortization).
__global__ __launch_bounds__(256, 2) void gemm1_kernel(
    const bf16* __restrict__ xb, const bf16* __restrict__ wgu,
    const int* __restrict__ counts, const int* __restrict__ offsets,
    const int* __restrict__ ids, bf16* __restrict__ H)
{
  const int e = blockIdx.z;
  const int cnt = counts[e];
  const int row0 = blockIdx.y * 128;
  if (row0 >= cnt) return;
  const int c0 = blockIdx.x * 128;              // F col tile in [0, 2048)

  __shared__ bf16 lA[128 * 32];
  __shared__ bf16 lBg[128 * 32];
  __shared__ bf16 lBu[128 * 32];

  const int tid  = threadIdx.x;
  const int lane = tid & 63;
  const int wave = tid >> 6;
  const int l4 = lane >> 2;
  const int kb = (lane & 3) * 8;

  const int ra0 = wave * 16 + l4;
  const int ra1 = (wave + 4) * 16 + l4;

  const int* ide = ids + e * N_TOK;
  const int m0 = min(row0 + ra0, cnt - 1);
  const int m1 = min(row0 + ra1, cnt - 1);
  const bf16* srcA0 = xb + (size_t)ide[m0] * D_MODEL + kb;
  const bf16* srcA1 = xb + (size_t)ide[m1] * D_MODEL + kb;
  const bf16* wge = wgu + (size_t)e * D_GU * D_MODEL;
  // gate rows: [c0, c0+128); up rows: [D_FF + c0, D_FF + c0 + 128)
  const bf16* srcBg0 = wge + (size_t)(c0 + ra0) * D_MODEL + kb;
  const bf16* srcBg1 = wge + (size_t)(c0 + ra1) * D_MODEL + kb;
  const bf16* srcBu0 = wge + (size_t)(D_FF + c0 + ra0) * D_MODEL + kb;
  const bf16* srcBu1 = wge + (size_t)(D_FF + c0 + ra1) * D_MODEL + kb;

  char* dA0  = (char*)lA  + wave * 1024;
  char* dA1  = (char*)lA  + (wave + 4) * 1024;
  char* dBg0 = (char*)lBg + wave * 1024;
  char* dBg1 = (char*)lBg + (wave + 4) * 1024;
  char* dBu0 = (char*)lBu + wave * 1024;
  char* dBu1 = (char*)lBu + (wave + 4) * 1024;

  const int wm = wave >> 1;
  const int wn = wave & 1;
  const int fr = lane & 15;
  const int fq = lane >> 4;
  const bf16* pA  = lA  + (wm * 64 + fr) * 32 + fq * 8;
  const bf16* pBg = lBg + (wn * 64 + fr) * 32 + fq * 8;
  const bf16* pBu = lBu + (wn * 64 + fr) * 32 + fq * 8;

  f32x4 accg[4][4], accu[4][4];
#pragma unroll
  for (int i = 0; i < 4; ++i)
#pragma unroll
    for (int j = 0; j < 4; ++j)
#pragma unroll
      for (int k = 0; k < 4; ++k) { accg[i][j][k] = 0.f; accu[i][j][k] = 0.f; }

  for (int kt = 0; kt < D_MODEL / 32; ++kt) {
    cp16(dA0, srcA0);   cp16(dA1, srcA1);
    cp16(dBg0, srcBg0); cp16(dBg1, srcBg1);
    cp16(dBu0, srcBu0); cp16(dBu1, srcBu1);
    srcA0 += 32; srcA1 += 32;
    srcBg0 += 32; srcBg1 += 32;
    srcBu0 += 32; srcBu1 += 32;
    __syncthreads();
    bf16x8 a[4];
#pragma unroll
    for (int fm = 0; fm < 4; ++fm) a[fm] = *(const bf16x8*)(pA + fm * 16 * 32);
#pragma unroll
    for (int fn = 0; fn < 4; ++fn) {
      bf16x8 bg = *(const bf16x8*)(pBg + fn * 16 * 32);
#pragma unroll
      for (int fm = 0; fm < 4; ++fm) accg[fm][fn] = mfma16(a[fm], bg, accg[fm][fn]);
    }
#pragma unroll
    for (int fn = 0; fn < 4; ++fn) {
      bf16x8 bu = *(const bf16x8*)(pBu + fn * 16 * 32);
#pragma unroll
      for (int fm = 0; fm < 4; ++fm) accu[fm][fn] = mfma16(a[fm], bu, accu[fm][fn]);
    }
    __syncthreads();
  }

  // epilogue: h = silu(up) * gate, computed in fp32 pre-rounding
  const int hbase = offsets[e] + row0;
#pragma unroll
  for (int fm = 0; fm < 4; ++fm) {
#pragma unroll
    for (int fn = 0; fn < 4; ++fn) {
#pragma unroll
      for (int i = 0; i < 4; ++i) {
        int m = wm * 64 + fm * 16 + fq * 4 + i;   // C/D: row = quad*4+reg
        if (row0 + m < cnt) {
          int col = c0 + wn * 64 + fn * 16 + fr;  // C/D: col = lane&15
          float g = accg[fm][fn][i];
          float u = accu[fm][fn][i];
          H[(size_t)(hbase + m) * D_FF + col] = (bf16)(g * u / (1.f + expf(-u)));
        }
      }
    }
  }
}

// ====== GEMM2: H (pitch 2048) @ Wd_b^T -> atomicAdd(w*acc) into fp32 out ======
__global__ __launch_bounds__(256, 2) void gemm2_kernel(
    const bf16* __restrict__ H, const bf16* __restrict__ wdb,
    const int* __restrict__ counts, const int* __restrict__ offsets,
    const int* __restrict__ ids, const float* __restrict__ wts,
    float* __restrict__ out)
{
  const int e = blockIdx.z;
  const int cnt = counts[e];
  const int row0 = blockIdx.y * 128;
  if (row0 >= cnt) return;
  const int c0 = blockIdx.x * 128;              // output col tile in [0, 1024)
  const int base = offsets[e];

  __shared__ bf16 lA[128 * 32];
  __shared__ bf16 lB[128 * 32];

  const int tid  = threadIdx.x;
  const int lane = tid & 63;
  const int wave = tid >> 6;
  const int l4 = lane >> 2;
  const int kb = (lane & 3) * 8;

  const int ra0 = wave * 16 + l4;
  const int ra1 = (wave + 4) * 16 + l4;
  const int m0 = min(row0 + ra0, cnt - 1);
  const int m1 = min(row0 + ra1, cnt - 1);
  const bf16* srcA0 = H + (size_t)(base + m0) * D_FF + kb;   // pitch 2048
  const bf16* srcA1 = H + (size_t)(base + m1) * D_FF + kb;
  const bf16* wde = wdb + (size_t)e * D_MODEL * D_FF;
  const bf16* srcB0 = wde + (size_t)(c0 + ra0) * D_FF + kb;
  const bf16* srcB1 = wde + (size_t)(c0 + ra1) * D_FF + kb;

  char* dA0 = (char*)lA + wave * 1024;
  char* dA1 = (char*)lA + (wave + 4) * 1024;
  char* dB0 = (char*)lB + wave * 1024;
  char* dB1 = (char*)lB + (wave + 4) * 1024;

  const int wm = wave >> 1;
  const int wn = wave & 1;
  const int fr = lane & 15;
  const int fq = lane >> 4;
  const bf16* pA = lA + (wm * 64 + fr) * 32 + fq * 8;
  const bf16* pB = lB + (wn * 64 + fr) * 32 + fq * 8;

  f32x4 acc[4][4];
#pragma unroll
  for (int i = 0; i < 4; ++i)
#pragma unroll
    for (int j = 0; j < 4; ++j)
#pragma unroll
      for (int k = 0; k < 4; ++k) acc[i][j][k] = 0.f;

  for (int kt = 0; kt < D_FF / 32; ++kt) {
    cp16(dA0, srcA0); cp16(dA1, srcA1);
    cp16(dB0, srcB0); cp16(dB1, srcB1);
    srcA0 += 32; srcA1 += 32; srcB0 += 32; srcB1 += 32;
    __syncthreads();
    bf16x8 a[4];
#pragma unroll
    for (int fm = 0; fm < 4; ++fm) a[fm] = *(const bf16x8*)(pA + fm * 16 * 32);
#pragma unroll
    for (int fn = 0; fn < 4; ++fn) {
      bf16x8 b = *(const bf16x8*)(pB + fn * 16 * 32);
#pragma unroll
      for (int fm = 0; fm < 4; ++fm) acc[fm][fn] = mfma16(a[fm], b, acc[fm][fn]);
    }
    __syncthreads();
  }

  const int* ide = ids + e * N_TOK;
  const float* wte = wts + e * N_TOK;
#pragma unroll
  for (int fm = 0; fm < 4; ++fm) {
#pragma unroll
    for (int i = 0; i < 4; ++i) {
      int m = wm * 64 + fm * 16 + fq * 4 + i;
      if (row0 + m < cnt) {
        int   tok = ide[row0 + m];
        float w   = wte[row0 + m];
        float* orow = out + (size_t)tok * D_MODEL;
#pragma unroll
        for (int fn = 0; fn < 4; ++fn) {
          int col = c0 + wn * 64 + fn * 16 + fr;
          atomicAdd(orow + col, w * acc[fm][fn][i]);
        }
      }
    }
  }
}

// =========================================================================================
extern "C" void kernel_launch(void* const* d_in, const int* in_sizes, int n_in,
                              void* d_out, int out_size, void* d_ws, size_t ws_size,
                              hipStream_t stream) {
  const float* x   = (const float*)d_in[0];
  const float* wr  = (const float*)d_in[1];
  const float* wgu = (const float*)d_in[2];
  const float* wd  = (const float*)d_in[3];
  float* out = (float*)d_out;

  char* ws = (char*)d_ws;
  // workspace layout
  int*   counts  = (int*)ws;                             // 32 B
  int*   offsets = (int*)(ws + 64);                      // 32 B
  int*   ids     = (int*)(ws + 4096);                    // 128 KB
  float* wts     = (float*)(ws + 4096 + 131072);         // 128 KB
  bf16*  xb      = (bf16*)(ws + 524288);                 // 8 MB
  bf16*  wgub    = (bf16*)(ws + 524288 + 8388608);       // 64 MB (reused for wdb after gemm1)
  bf16*  wdb     = wgub;                                 // 32 MB alias (wgub dead post-gemm1)
  bf16*  H       = (bf16*)(ws + 524288 + 8388608 + 67108864);  // 8192 x 2048 bf16 = 32 MB

  hipMemsetAsync(counts, 0, 64, stream);
  hipMemsetAsync(out, 0, (size_t)N_TOK * D_MODEL * sizeof(float), stream);
  router_kernel<<<N_TOK / 32, 256, 0, stream>>>(x, wr, counts, ids, wts, xb);
  offsets_kernel<<<1, 64, 0, stream>>>(counts, offsets);
  cvt_kernel<<<2048, 256, 0, stream>>>(wgu, wgub, (N_EXP * D_GU * D_MODEL) / 8);
  gemm1_kernel<<<dim3(D_FF / 128, N_TOK / 128, N_EXP), 256, 0, stream>>>(
      xb, wgub, counts, offsets, ids, H);
  cvt_kernel<<<2048, 256, 0, stream>>>(wd, wdb, (N_EXP * D_MODEL * D_FF) / 8);
  gemm2_kernel<<<dim3(D_MODEL / 128, N_TOK / 128, N_EXP), 256, 0, stream>>>(
      H, wdb, counts, offsets, ids, wts, out);
}